// Round 2
// baseline (402.629 us; speedup 1.0000x reference)
//
#include <hip/hip_runtime.h>

// Problem constants (match reference: B=8, N=8192, D=64, NNZ=2097152)
#define NB 8
#define NN 8192
#define ND 64

// ---------------------------------------------------------------------------
// Mask normalization: the harness's bool-upload convention (1-byte bool vs
// int32) is unspecified. Detect on-device: interpret X_mask as uint32 words;
// if masks were uploaded as int32 0/1, every word is <=1. If uploaded as
// bytes, words are 4 packed random 0/1 bytes -> almost surely some word > 1
// within the first 256 words. Normalize both masks into uint32 0/1 in ws.
// ---------------------------------------------------------------------------
__global__ void mask_prep_kernel(const void* __restrict__ xm_raw,
                                 const void* __restrict__ tm_raw,
                                 unsigned int* __restrict__ xm_out,
                                 unsigned int* __restrict__ tm_out,
                                 int n) {
    __shared__ int s_is_bytes;
    if (threadIdx.x == 0) {
        const unsigned int* w = (const unsigned int*)xm_raw;
        int ib = 0;
        for (int i = 0; i < 256; ++i) {
            if (w[i] > 1u) { ib = 1; break; }
        }
        s_is_bytes = ib;
    }
    __syncthreads();
    const int idx = blockIdx.x * blockDim.x + threadIdx.x;
    if (idx >= n) return;
    unsigned int xv, tv;
    if (s_is_bytes) {
        xv = ((const unsigned char*)xm_raw)[idx];
        tv = ((const unsigned char*)tm_raw)[idx];
    } else {
        xv = ((const unsigned int*)xm_raw)[idx];
        tv = ((const unsigned int*)tm_raw)[idx];
    }
    xm_out[idx] = xv ? 1u : 0u;
    tm_out[idx] = tv ? 1u : 0u;
}

// ---------------------------------------------------------------------------
// COO scatter: one 64-lane group per nnz (lane == d, D=64 == wavefront).
// out[b,row,d] += val * (X_mask[b,col] ? X[b,col,d] : 0), only where
// tarX_mask[b,row] is set (masked-out rows stay at the memset 0).
// ---------------------------------------------------------------------------
__global__ void coo_scatter_kernel(const int* __restrict__ Ab,
                                   const int* __restrict__ Ar,
                                   const int* __restrict__ Ac,
                                   const float* __restrict__ Av,
                                   const float* __restrict__ X,
                                   const unsigned int* __restrict__ Xm,
                                   const unsigned int* __restrict__ Tm,
                                   float* __restrict__ out,
                                   int nnz) {
    const int groups_per_block = blockDim.x >> 6;            // 64-lane groups
    const int g0   = blockIdx.x * groups_per_block + (threadIdx.x >> 6);
    const int gstr = gridDim.x * groups_per_block;
    const int lane = threadIdx.x & 63;

    for (int e = g0; e < nnz; e += gstr) {
        const int b = Ab[e];
        const int r = Ar[e];
        // output-mask filter first: skips gather + atomic entirely
        if (!Tm[b * NN + r]) continue;
        const int c = Ac[e];
        if (!Xm[b * NN + c]) continue;
        const float v = Av[e];
        const float x = X[((size_t)(b * NN + c)) * ND + lane];
        atomicAdd(&out[((size_t)(b * NN + r)) * ND + lane], v * x);
    }
}

extern "C" void kernel_launch(void* const* d_in, const int* in_sizes, int n_in,
                              void* d_out, int out_size, void* d_ws, size_t ws_size,
                              hipStream_t stream) {
    const int*   Ab = (const int*)d_in[0];
    const int*   Ar = (const int*)d_in[1];
    const int*   Ac = (const int*)d_in[2];
    const float* Av = (const float*)d_in[3];
    const float* X  = (const float*)d_in[4];
    const void*  Xm_raw = d_in[5];
    const void*  Tm_raw = d_in[6];
    float* out = (float*)d_out;

    const int nnz   = in_sizes[0];
    const int nmask = in_sizes[5];   // B*N

    unsigned int* xm = (unsigned int*)d_ws;
    unsigned int* tm = xm + nmask;

    // out must be exactly 0 where masked / no contributions (harness poisons 0xAA)
    hipMemsetAsync(d_out, 0, (size_t)out_size * sizeof(float), stream);

    mask_prep_kernel<<<(nmask + 255) / 256, 256, 0, stream>>>(Xm_raw, Tm_raw, xm, tm, nmask);

    // grid-stride: 16384 blocks x 4 groups = 65536 groups, ~32 nnz each
    coo_scatter_kernel<<<16384, 256, 0, stream>>>(Ab, Ar, Ac, Av, X, xm, tm, out, nnz);
}

// Round 4
// 344.333 us; speedup vs baseline: 1.1693x; 1.1693x over previous
//
#include <hip/hip_runtime.h>

// Problem constants (reference: B=8, N=8192, D=64, NNZ=2097152)
#define NB 8
#define NN 8192
#define ND 64
#define SCAN_THREADS 1024

// ---------------------------------------------------------------------------
// Mask normalization (bool upload convention unknown: 1-byte vs int32).
// Detect on-device from X_mask word values; normalize both masks to u32 0/1.
// ---------------------------------------------------------------------------
__global__ void mask_prep_kernel(const void* __restrict__ xm_raw,
                                 const void* __restrict__ tm_raw,
                                 unsigned int* __restrict__ xm_out,
                                 unsigned int* __restrict__ tm_out,
                                 int n) {
    __shared__ int s_is_bytes;
    if (threadIdx.x == 0) {
        const unsigned int* w = (const unsigned int*)xm_raw;
        int ib = 0;
        for (int i = 0; i < 256; ++i) {
            if (w[i] > 1u) { ib = 1; break; }
        }
        s_is_bytes = ib;
    }
    __syncthreads();
    const int idx = blockIdx.x * blockDim.x + threadIdx.x;
    if (idx >= n) return;
    unsigned int xv, tv;
    if (s_is_bytes) {
        xv = ((const unsigned char*)xm_raw)[idx];
        tv = ((const unsigned char*)tm_raw)[idx];
    } else {
        xv = ((const unsigned int*)xm_raw)[idx];
        tv = ((const unsigned int*)tm_raw)[idx];
    }
    xm_out[idx] = xv ? 1u : 0u;
    tm_out[idx] = tv ? 1u : 0u;
}

// ---------------------------------------------------------------------------
// Pass 1: per-segment (b*N+row) count of nnz that survive BOTH masks.
// Counters are 256 KB -> L2-resident atomics, cheap.
// ---------------------------------------------------------------------------
__global__ void count_kernel(const int* __restrict__ Ab,
                             const int* __restrict__ Ar,
                             const int* __restrict__ Ac,
                             const unsigned int* __restrict__ Xm,
                             const unsigned int* __restrict__ Tm,
                             unsigned int* __restrict__ cnt, int nnz) {
    int e = blockIdx.x * blockDim.x + threadIdx.x;
    const int str = gridDim.x * blockDim.x;
    for (; e < nnz; e += str) {
        const int b = Ab[e];
        const int seg = b * NN + Ar[e];
        if (Tm[seg] && Xm[b * NN + Ac[e]]) atomicAdd(&cnt[seg], 1u);
    }
}

// ---------------------------------------------------------------------------
// Pass 2: exclusive scan of 65536 counters, single block of 1024 threads
// (64 elements each: sequential chunk sums -> LDS Hillis-Steele -> writeback).
// Writes starts[] (segment base) and cursor[] (working copy for pass 3).
// ---------------------------------------------------------------------------
__global__ void scan_kernel(const unsigned int* __restrict__ cnt,
                            unsigned int* __restrict__ starts,
                            unsigned int* __restrict__ cursor, int n) {
    __shared__ unsigned int s[SCAN_THREADS];
    const int t = threadIdx.x;
    const int chunk = n / SCAN_THREADS;  // 64
    unsigned int sum = 0;
    for (int i = 0; i < chunk; ++i) sum += cnt[t * chunk + i];
    s[t] = sum;
    __syncthreads();
    for (int off = 1; off < SCAN_THREADS; off <<= 1) {
        unsigned int v = (t >= off) ? s[t - off] : 0u;
        __syncthreads();
        if (t >= off) s[t] += v;
        __syncthreads();
    }
    unsigned int base = (t == 0) ? 0u : s[t - 1];
    for (int i = 0; i < chunk; ++i) {
        const unsigned int c = cnt[t * chunk + i];
        starts[t * chunk + i] = base;
        cursor[t * chunk + i] = base;
        base += c;
    }
}

// ---------------------------------------------------------------------------
// Pass 3: scatter surviving (x_row, val) pairs into segment-sorted order.
// x_row is pre-linearized (b*N+col) so pass 4 indexes X directly.
// ---------------------------------------------------------------------------
__global__ void scatter_pairs_kernel(const int* __restrict__ Ab,
                                     const int* __restrict__ Ar,
                                     const int* __restrict__ Ac,
                                     const float* __restrict__ Av,
                                     const unsigned int* __restrict__ Xm,
                                     const unsigned int* __restrict__ Tm,
                                     unsigned int* __restrict__ cursor,
                                     int* __restrict__ cols,
                                     float* __restrict__ vals, int nnz) {
    int e = blockIdx.x * blockDim.x + threadIdx.x;
    const int str = gridDim.x * blockDim.x;
    for (; e < nnz; e += str) {
        const int b = Ab[e];
        const int seg = b * NN + Ar[e];
        const int xrow = b * NN + Ac[e];
        if (Tm[seg] && Xm[xrow]) {
            const unsigned int pos = atomicAdd(&cursor[seg], 1u);
            cols[pos] = xrow;
            vals[pos] = Av[e];
        }
    }
}

// ---------------------------------------------------------------------------
// Pass 4: one 64-lane group per segment (lane == d). Register accumulation,
// single coalesced 256B write per output row. No output atomics.
// ---------------------------------------------------------------------------
__global__ void gather_accum_kernel(const unsigned int* __restrict__ starts,
                                    const unsigned int* __restrict__ cnt,
                                    const int* __restrict__ cols,
                                    const float* __restrict__ vals,
                                    const float* __restrict__ X,
                                    float* __restrict__ out, int nseg) {
    const int g = blockIdx.x * (blockDim.x >> 6) + (threadIdx.x >> 6);
    if (g >= nseg) return;
    const unsigned int n = cnt[g];
    if (n == 0) return;  // memset-0 output is already correct
    const int lane = threadIdx.x & 63;
    const unsigned int k0 = starts[g];
    const unsigned int end = k0 + n;
    float acc = 0.f;
    #pragma unroll 4
    for (unsigned int k = k0; k < end; ++k) {
        const int xrow = cols[k];     // uniform across the group
        const float v = vals[k];
        acc = fmaf(v, X[((size_t)xrow << 6) + lane], acc);
    }
    out[((size_t)g << 6) + lane] = acc;
}

// ---------------------------------------------------------------------------
// Fallback: round-2 proven atomic scatter (used only if ws_size is too small
// for the sort buffers).
// ---------------------------------------------------------------------------
__global__ void coo_scatter_kernel(const int* __restrict__ Ab,
                                   const int* __restrict__ Ar,
                                   const int* __restrict__ Ac,
                                   const float* __restrict__ Av,
                                   const float* __restrict__ X,
                                   const unsigned int* __restrict__ Xm,
                                   const unsigned int* __restrict__ Tm,
                                   float* __restrict__ out, int nnz) {
    const int groups_per_block = blockDim.x >> 6;
    const int g0 = blockIdx.x * groups_per_block + (threadIdx.x >> 6);
    const int gstr = gridDim.x * groups_per_block;
    const int lane = threadIdx.x & 63;
    for (int e = g0; e < nnz; e += gstr) {
        const int b = Ab[e];
        const int r = Ar[e];
        if (!Tm[b * NN + r]) continue;
        const int c = Ac[e];
        if (!Xm[b * NN + c]) continue;
        const float v = Av[e];
        const float x = X[((size_t)(b * NN + c)) * ND + lane];
        atomicAdd(&out[((size_t)(b * NN + r)) * ND + lane], v * x);
    }
}

extern "C" void kernel_launch(void* const* d_in, const int* in_sizes, int n_in,
                              void* d_out, int out_size, void* d_ws, size_t ws_size,
                              hipStream_t stream) {
    const int*   Ab = (const int*)d_in[0];
    const int*   Ar = (const int*)d_in[1];
    const int*   Ac = (const int*)d_in[2];
    const float* Av = (const float*)d_in[3];
    const float* X  = (const float*)d_in[4];
    const void*  Xm_raw = d_in[5];
    const void*  Tm_raw = d_in[6];
    float* out = (float*)d_out;

    const int nnz   = in_sizes[0];
    const int nmask = in_sizes[5];   // B*N = 65536

    // Workspace layout (all 4-byte aligned)
    unsigned char* w = (unsigned char*)d_ws;
    unsigned int* xm     = (unsigned int*)w;                 w += (size_t)nmask * 4;
    unsigned int* tm     = (unsigned int*)w;                 w += (size_t)nmask * 4;
    unsigned int* cnt    = (unsigned int*)w;                 w += (size_t)nmask * 4;
    unsigned int* starts = (unsigned int*)w;                 w += (size_t)nmask * 4;
    unsigned int* cursor = (unsigned int*)w;                 w += (size_t)nmask * 4;
    int*          cols   = (int*)w;                          w += (size_t)nnz * 4;
    float*        vals   = (float*)w;                        w += (size_t)nnz * 4;
    const size_t needed = (size_t)(w - (unsigned char*)d_ws);

    hipMemsetAsync(d_out, 0, (size_t)out_size * sizeof(float), stream);
    mask_prep_kernel<<<(nmask + 255) / 256, 256, 0, stream>>>(Xm_raw, Tm_raw, xm, tm, nmask);

    if (ws_size < needed) {
        // Fallback: proven atomic path
        coo_scatter_kernel<<<16384, 256, 0, stream>>>(Ab, Ar, Ac, Av, X, xm, tm, out, nnz);
        return;
    }

    hipMemsetAsync(cnt, 0, (size_t)nmask * 4, stream);

    const int nblk = 4096;  // grid-stride over 2M nnz
    count_kernel<<<nblk, 256, 0, stream>>>(Ab, Ar, Ac, xm, tm, cnt, nnz);
    scan_kernel<<<1, SCAN_THREADS, 0, stream>>>(cnt, starts, cursor, nmask);
    scatter_pairs_kernel<<<nblk, 256, 0, stream>>>(Ab, Ar, Ac, Av, xm, tm, cursor, cols, vals, nnz);
    gather_accum_kernel<<<(nmask * 64 + 255) / 256, 256, 0, stream>>>(starts, cnt, cols, vals, X, out, nmask);
}

// Round 5
// 201.016 us; speedup vs baseline: 2.0030x; 1.7130x over previous
//
#include <hip/hip_runtime.h>

// Problem constants (reference: B=8, N=8192, D=64, NNZ=2097152)
#define NB 8
#define NN 8192
#define ND 64

// ---------------------------------------------------------------------------
// Mask normalization (bool upload convention unknown: 1-byte vs int32).
// Detection is wave-parallel: threads 0..255 of each block test one word of
// X_mask; any word > 1 => byte-packed bools.
// ---------------------------------------------------------------------------
__global__ void mask_prep_kernel(const void* __restrict__ xm_raw,
                                 const void* __restrict__ tm_raw,
                                 unsigned int* __restrict__ xm_out,
                                 unsigned int* __restrict__ tm_out,
                                 int n) {
    __shared__ int s_is_bytes;
    if (threadIdx.x == 0) s_is_bytes = 0;
    __syncthreads();
    {
        const unsigned int* w = (const unsigned int*)xm_raw;
        if (threadIdx.x < 256 && w[threadIdx.x] > 1u) atomicOr(&s_is_bytes, 1);
    }
    __syncthreads();
    const int idx = blockIdx.x * blockDim.x + threadIdx.x;
    if (idx >= n) return;
    unsigned int xv, tv;
    if (s_is_bytes) {
        xv = ((const unsigned char*)xm_raw)[idx];
        tv = ((const unsigned char*)tm_raw)[idx];
    } else {
        xv = ((const unsigned int*)xm_raw)[idx];
        tv = ((const unsigned int*)tm_raw)[idx];
    }
    xm_out[idx] = xv ? 1u : 0u;
    tm_out[idx] = tv ? 1u : 0u;
}

// ---------------------------------------------------------------------------
// Pass 1: per-segment (b*N+row) survivor counts. 256 KB counters, L2 atomics.
// ---------------------------------------------------------------------------
__global__ void count_kernel(const int* __restrict__ Ab,
                             const int* __restrict__ Ar,
                             const int* __restrict__ Ac,
                             const unsigned int* __restrict__ Xm,
                             const unsigned int* __restrict__ Tm,
                             unsigned int* __restrict__ cnt, int nnz) {
    int e = blockIdx.x * blockDim.x + threadIdx.x;
    const int str = gridDim.x * blockDim.x;
    for (; e < nnz; e += str) {
        const int b = Ab[e];
        const int seg = b * NN + Ar[e];
        if (Tm[seg] && Xm[b * NN + Ac[e]]) atomicAdd(&cnt[seg], 1u);
    }
}

// ---------------------------------------------------------------------------
// Pass 2a: hierarchical scan, stage A. 256 blocks x 256 threads.
// Per-block exclusive scan of cnt -> starts (block-local), block total ->
// blocksums[bid].
// ---------------------------------------------------------------------------
__global__ void scanA_kernel(const unsigned int* __restrict__ cnt,
                             unsigned int* __restrict__ starts,
                             unsigned int* __restrict__ blocksums) {
    __shared__ unsigned int s[256];
    const int t = threadIdx.x;
    const int gid = blockIdx.x * 256 + t;
    const unsigned int c = cnt[gid];
    s[t] = c;
    __syncthreads();
    for (int off = 1; off < 256; off <<= 1) {
        unsigned int v = (t >= off) ? s[t - off] : 0u;
        __syncthreads();
        if (t >= off) s[t] += v;
        __syncthreads();
    }
    starts[gid] = s[t] - c;                       // exclusive, block-local
    if (t == 255) blocksums[blockIdx.x] = s[255];
}

// ---------------------------------------------------------------------------
// Pass 2b: stage B. Each block redundantly scans the 256 blocksums in LDS,
// adds its block offset, writes final starts + cursor.
// ---------------------------------------------------------------------------
__global__ void scanB_kernel(const unsigned int* __restrict__ blocksums,
                             unsigned int* __restrict__ starts,
                             unsigned int* __restrict__ cursor) {
    __shared__ unsigned int s[256];
    const int t = threadIdx.x;
    const int gid = blockIdx.x * 256 + t;
    s[t] = blocksums[t];
    __syncthreads();
    for (int off = 1; off < 256; off <<= 1) {
        unsigned int v = (t >= off) ? s[t - off] : 0u;
        __syncthreads();
        if (t >= off) s[t] += v;
        __syncthreads();
    }
    const unsigned int offset = (blockIdx.x == 0) ? 0u : s[blockIdx.x - 1];
    const unsigned int v = starts[gid] + offset;
    starts[gid] = v;
    cursor[gid] = v;
}

// ---------------------------------------------------------------------------
// Pass 3: scatter surviving (x_row, val) as a packed int2 (single 8B store).
// ---------------------------------------------------------------------------
__global__ void scatter_pairs_kernel(const int* __restrict__ Ab,
                                     const int* __restrict__ Ar,
                                     const int* __restrict__ Ac,
                                     const float* __restrict__ Av,
                                     const unsigned int* __restrict__ Xm,
                                     const unsigned int* __restrict__ Tm,
                                     unsigned int* __restrict__ cursor,
                                     int2* __restrict__ pairs, int nnz) {
    int e = blockIdx.x * blockDim.x + threadIdx.x;
    const int str = gridDim.x * blockDim.x;
    for (; e < nnz; e += str) {
        const int b = Ab[e];
        const int seg = b * NN + Ar[e];
        const int xrow = b * NN + Ac[e];
        if (Tm[seg] && Xm[xrow]) {
            const unsigned int pos = atomicAdd(&cursor[seg], 1u);
            pairs[pos] = make_int2(xrow, __float_as_int(Av[e]));
        }
    }
}

// ---------------------------------------------------------------------------
// Pass 4: one 64-lane group per segment (lane == d). Register accumulation,
// single coalesced 256B write per output row. No output atomics.
// ---------------------------------------------------------------------------
__global__ void gather_accum_kernel(const unsigned int* __restrict__ starts,
                                    const unsigned int* __restrict__ cnt,
                                    const int2* __restrict__ pairs,
                                    const float* __restrict__ X,
                                    float* __restrict__ out, int nseg) {
    const int g = blockIdx.x * (blockDim.x >> 6) + (threadIdx.x >> 6);
    if (g >= nseg) return;
    const unsigned int n = cnt[g];
    if (n == 0) return;  // memset-0 output already correct
    const int lane = threadIdx.x & 63;
    const unsigned int k0 = starts[g];
    const unsigned int end = k0 + n;
    float acc = 0.f;
    #pragma unroll 4
    for (unsigned int k = k0; k < end; ++k) {
        const int2 p = pairs[k];                  // uniform across the group
        acc = fmaf(__int_as_float(p.y), X[((size_t)p.x << 6) + lane], acc);
    }
    out[((size_t)g << 6) + lane] = acc;
}

// ---------------------------------------------------------------------------
// Fallback: round-2 proven atomic scatter (ws too small OR unexpected shape).
// ---------------------------------------------------------------------------
__global__ void coo_scatter_kernel(const int* __restrict__ Ab,
                                   const int* __restrict__ Ar,
                                   const int* __restrict__ Ac,
                                   const float* __restrict__ Av,
                                   const float* __restrict__ X,
                                   const unsigned int* __restrict__ Xm,
                                   const unsigned int* __restrict__ Tm,
                                   float* __restrict__ out, int nnz) {
    const int groups_per_block = blockDim.x >> 6;
    const int g0 = blockIdx.x * groups_per_block + (threadIdx.x >> 6);
    const int gstr = gridDim.x * groups_per_block;
    const int lane = threadIdx.x & 63;
    for (int e = g0; e < nnz; e += gstr) {
        const int b = Ab[e];
        const int r = Ar[e];
        if (!Tm[b * NN + r]) continue;
        const int c = Ac[e];
        if (!Xm[b * NN + c]) continue;
        const float v = Av[e];
        const float x = X[((size_t)(b * NN + c)) * ND + lane];
        atomicAdd(&out[((size_t)(b * NN + r)) * ND + lane], v * x);
    }
}

extern "C" void kernel_launch(void* const* d_in, const int* in_sizes, int n_in,
                              void* d_out, int out_size, void* d_ws, size_t ws_size,
                              hipStream_t stream) {
    const int*   Ab = (const int*)d_in[0];
    const int*   Ar = (const int*)d_in[1];
    const int*   Ac = (const int*)d_in[2];
    const float* Av = (const float*)d_in[3];
    const float* X  = (const float*)d_in[4];
    const void*  Xm_raw = d_in[5];
    const void*  Tm_raw = d_in[6];
    float* out = (float*)d_out;

    const int nnz   = in_sizes[0];
    const int nmask = in_sizes[5];   // B*N = 65536

    // Workspace layout (8B-aligned pairs buffer)
    unsigned char* w = (unsigned char*)d_ws;
    unsigned int* xm        = (unsigned int*)w;  w += (size_t)nmask * 4;
    unsigned int* tm        = (unsigned int*)w;  w += (size_t)nmask * 4;
    unsigned int* cnt       = (unsigned int*)w;  w += (size_t)nmask * 4;
    unsigned int* starts    = (unsigned int*)w;  w += (size_t)nmask * 4;
    unsigned int* cursor    = (unsigned int*)w;  w += (size_t)nmask * 4;
    unsigned int* blocksums = (unsigned int*)w;  w += 256 * 4;
    w = (unsigned char*)(((size_t)w + 7) & ~(size_t)7);
    int2*         pairs     = (int2*)w;          w += (size_t)nnz * 8;
    const size_t needed = (size_t)(w - (unsigned char*)d_ws);

    hipMemsetAsync(d_out, 0, (size_t)out_size * sizeof(float), stream);
    mask_prep_kernel<<<(nmask + 255) / 256, 256, 0, stream>>>(Xm_raw, Tm_raw, xm, tm, nmask);

    // Hierarchical scan assumes nmask == 256*256; otherwise use atomic path.
    if (ws_size < needed || nmask != 65536) {
        coo_scatter_kernel<<<16384, 256, 0, stream>>>(Ab, Ar, Ac, Av, X, xm, tm, out, nnz);
        return;
    }

    hipMemsetAsync(cnt, 0, (size_t)nmask * 4, stream);

    const int nblk = 4096;  // grid-stride over 2M nnz
    count_kernel<<<nblk, 256, 0, stream>>>(Ab, Ar, Ac, xm, tm, cnt, nnz);
    scanA_kernel<<<256, 256, 0, stream>>>(cnt, starts, blocksums);
    scanB_kernel<<<256, 256, 0, stream>>>(blocksums, starts, cursor);
    scatter_pairs_kernel<<<nblk, 256, 0, stream>>>(Ab, Ar, Ac, Av, xm, tm, cursor, pairs, nnz);
    gather_accum_kernel<<<16384, 256, 0, stream>>>(starts, cnt, pairs, X, out, nmask);
}